// Round 12
// baseline (278.997 us; speedup 1.0000x reference)
//
#include <hip/hip_runtime.h>
#include <hip/hip_bf16.h>
#include <cstdint>

// ---------------------------------------------------------------------------
// GraphRLAgent: 2-layer GAT (heads=2 then 1) + global mean pool + 2 heads.
// Round 29: fuse bucket sort + layer-1 aggregation (block-local dependency:
// bucket b's counting sort produces exactly the CSR rows its own 32 nodes
// aggregate). Buckets 64->32 nodes (BSH=5) so the fused grid (~1564 blocks,
// 24 waves/CU) keeps agg concurrency >= R28's (R23 lesson: never starve the
// gather phase of waves). LDS ~8KB (no big-LDS co-tenant). rowptr/csr_src
// still emitted for agg_h1. Launches 9 -> 8. Everything else = R28 (274.4).
// ---------------------------------------------------------------------------

typedef __attribute__((ext_vector_type(8))) short bf16x8;
typedef __attribute__((ext_vector_type(4))) float f32x4;

#define NBLK_H 160   // edge chunks for hist/partition passes
#define BSH 5        // bucket shift: 32 nodes per bucket
#define BMSK 31
#define PCHUNK 256

__device__ __forceinline__ float wave_sum(float v) {
#pragma unroll
    for (int off = 32; off >= 1; off >>= 1) v += __shfl_xor(v, off, 64);
    return v;
}

__device__ __forceinline__ unsigned short f2bf(float f) {
    union { float f; uint32_t u; } c; c.f = f;
    uint32_t u = c.u;
    return (unsigned short)((u + 0x7fffu + ((u >> 16) & 1u)) >> 16);
}

__device__ __forceinline__ float bf2f(unsigned short u) {
    union { uint32_t u; float f; } c; c.u = ((uint32_t)u) << 16;
    return c.f;
}

// ------------------------- B swizzle body (ldW/colOff aware) --------------

template <int K, int FOUT>
__device__ __forceinline__ void swizzle_body(const float* __restrict__ W, int ldW, int colOff,
                                             unsigned short* __restrict__ Bsw, int tid) {
    constexpr int CPW = FOUT / 4, NCT = CPW / 16, KST = K / 32;
    if (tid >= K * FOUT / 8) return;
    int lane = tid & 63;
    int rest = tid >> 6;
    int t = rest % KST; rest /= KST;
    int c = rest % NCT; rest /= NCT;
    int cg_ = rest;
    int quad = lane >> 4, lo = lane & 15;
    int col = colOff + cg_ * CPW + c * 16 + lo;
    unsigned short v[8];
#pragma unroll
    for (int j = 0; j < 8; ++j)
        v[j] = f2bf(W[(t * 32 + quad * 8 + j) * ldW + col]);
    ushort4* dst = (ushort4*)(Bsw + (size_t)tid * 8);
    ushort4 o0, o1;
    o0.x = v[0]; o0.y = v[1]; o0.z = v[2]; o0.w = v[3];
    o1.x = v[4]; o1.y = v[5]; o1.z = v[6]; o1.w = v[7];
    dst[0] = o0; dst[1] = o1;
}

// ------------------------- init: zero + swizzles + v1 + edge hist ---------

__global__ __launch_bounds__(256) void init_kernel(
        const float* __restrict__ W1, const float* __restrict__ W2,
        const float* __restrict__ a_src1, const float* __restrict__ a_dst1,
        unsigned short* __restrict__ B1h0, unsigned short* __restrict__ B1h1,
        unsigned short* __restrict__ B2,
        float* __restrict__ v1s, float* __restrict__ v1d,
        int* __restrict__ zbase, int zn4, int ZB,
        const int* __restrict__ ei, int* __restrict__ hist,
        int E, int ET, int CHUNK, int NB) {
    __shared__ int bins[2048];
    int b = blockIdx.x;
    if (b < 8)        swizzle_body<128, 128>(W1, 256, 0,   B1h0, b * 256 + threadIdx.x);
    else if (b < 16)  swizzle_body<128, 128>(W1, 256, 128, B1h1, (b - 8) * 256 + threadIdx.x);
    else if (b < 32)  swizzle_body<256, 128>(W2, 128, 0,   B2, (b - 16) * 256 + threadIdx.x);
    else if (b == 32) {
        int t = threadIdx.x, h = t >> 7, k = t & 127;
        float vs = 0.f, vd = 0.f;
        for (int c = 0; c < 128; ++c) {
            float w = W1[k * 256 + h * 128 + c];
            vs += w * a_src1[h * 128 + c];
            vd += w * a_dst1[h * 128 + c];
        }
        v1s[h * 128 + k] = vs;
        v1d[h * 128 + k] = vd;
    } else if (b < 33 + ZB) {
        int i = (b - 33) * 256 + threadIdx.x;
        if (i < zn4) ((int4*)zbase)[i] = make_int4(0, 0, 0, 0);
    } else {
        const int blk = b - 33 - ZB;
        for (int t = threadIdx.x; t < NB; t += 256) bins[t] = 0;
        __syncthreads();
        const int start = blk * CHUNK, end = min(ET, start + CHUNK);
        for (int i = start + threadIdx.x; i < end; i += 256) {
            int dst = (i < E) ? ei[E + i] : (i - E);
            atomicAdd(&bins[dst >> BSH], 1);
        }
        __syncthreads();
        for (int t = threadIdx.x; t < NB; t += 256) hist[t * NBLK_H + blk] = bins[t];
    }
}

// ------------------------- scan_tiles + attn1_cast (fused launch) ---------

__global__ __launch_bounds__(256) void scan_attn1(
        int* __restrict__ hist, int* __restrict__ tsum, int M, int TILESH,
        const float* __restrict__ x, const float* __restrict__ v1s,
        const float* __restrict__ v1d, float* __restrict__ es1,
        float* __restrict__ ed1, unsigned short* __restrict__ xbf, int N) {
    __shared__ int buf[256];
    if ((int)blockIdx.x < TILESH) {
        const int t = threadIdx.x;
        const int base = blockIdx.x * 1024 + t * 4;
        int v[4]; int s = 0;
#pragma unroll
        for (int k = 0; k < 4; ++k) { v[k] = (base + k < M) ? hist[base + k] : 0; s += v[k]; }
        buf[t] = s;
        __syncthreads();
#pragma unroll
        for (int off = 1; off < 256; off <<= 1) {
            int xx = (t >= off) ? buf[t - off] : 0;
            __syncthreads();
            buf[t] += xx;
            __syncthreads();
        }
        int run = buf[t] - s;
#pragma unroll
        for (int k = 0; k < 4; ++k) {
            if (base + k < M) hist[base + k] = run;
            run += v[k];
        }
        if (t == 255) tsum[blockIdx.x] = buf[255];
        return;
    }
    int bid = blockIdx.x - TILESH;
    int wid = (bid * 256 + threadIdx.x) >> 6;
    int lane = threadIdx.x & 63;
    if (wid >= N) return;
    float2 xv = *(const float2*)(x + (size_t)wid * 128 + lane * 2);
    float p0s = xv.x * v1s[lane * 2] + xv.y * v1s[lane * 2 + 1];
    float p1s = xv.x * v1s[128 + lane * 2] + xv.y * v1s[128 + lane * 2 + 1];
    float p0d = xv.x * v1d[lane * 2] + xv.y * v1d[lane * 2 + 1];
    float p1d = xv.x * v1d[128 + lane * 2] + xv.y * v1d[128 + lane * 2 + 1];
    p0s = wave_sum(p0s); p1s = wave_sum(p1s);
    p0d = wave_sum(p0d); p1d = wave_sum(p1d);
    if (lane == 0) {
        es1[wid * 2] = p0s; es1[wid * 2 + 1] = p1s;
        ed1[wid * 2] = p0d; ed1[wid * 2 + 1] = p1d;
    }
    ushort2 o; o.x = f2bf(xv.x); o.y = f2bf(xv.y);
    *(ushort2*)(xbf + (size_t)wid * 128 + lane * 2) = o;
}

// ------------------------- partition (folds global scan) ------------------

__global__ __launch_bounds__(256) void part_kernel(const int* __restrict__ ei,
                                                   const int* __restrict__ hist,
                                                   const int* __restrict__ tsum,
                                                   int* __restrict__ bsorted,
                                                   int* __restrict__ segbase,
                                                   int E, int ET, int CHUNK, int NB, int T) {
    __shared__ int sb[256];
    __shared__ int scur[2048];
    const int t = threadIdx.x;
    sb[t] = (t < T) ? tsum[t] : 0;
    __syncthreads();
#pragma unroll
    for (int off = 1; off < 256; off <<= 1) {
        int v = (t >= off) ? sb[t - off] : 0;
        __syncthreads();
        sb[t] += v;
        __syncthreads();
    }
    const int blk = blockIdx.x;
    for (int b = t; b < NB; b += 256) {
        int idx = b * NBLK_H + blk;
        int tile = idx >> 10;
        int v = hist[idx] + (tile ? sb[tile - 1] : 0);
        scur[b] = v;
        if (blk == 0) segbase[b] = v;
    }
    if (blk == 0 && t == 0) segbase[NB] = sb[T - 1];
    __syncthreads();
    const int start = blk * CHUNK, end = min(ET, start + CHUNK);
    for (int i = start + t; i < end; i += 256) {
        int dst = (i < E) ? ei[E + i] : (i - E);
        int src = (i < E) ? ei[i] : dst;
        int pos = atomicAdd(&scur[dst >> BSH], 1);
        bsorted[pos] = (src << BSH) | (dst & BMSK);
    }
}

// ------------------------- fused bucket sort + layer-1 aggregation --------
// Phase A: counting sort of this bucket's 32 dst nodes (ebuf stash; emits
// rowptr + csr_src globally for agg_h1, rstart[] in LDS for phase B).
// Phase B: R28 2-nodes-per-wave inline-softmax aggregation of the SAME 32
// nodes (4 passes of 8); csr_src reads are L2-hot (written in phase A; HIP
// guarantees same-block global RAW visibility after __syncthreads).
// NOTE: macro params must not be named x/y/z/w (token substitution).

#define ACC2(U_, WW_, P_, Q_) { float v_;                              \
    v_ = bf2f(U_.x); P_.x += WW_.x * v_; Q_.x += WW_.y * v_;           \
    v_ = bf2f(U_.y); P_.y += WW_.x * v_; Q_.y += WW_.y * v_;           \
    v_ = bf2f(U_.z); P_.z += WW_.x * v_; Q_.z += WW_.y * v_;           \
    v_ = bf2f(U_.w); P_.w += WW_.x * v_; Q_.w += WW_.y * v_; }

__global__ __launch_bounds__(256) void bucket_agg(
        const int* __restrict__ bsorted, const int* __restrict__ segbase,
        const unsigned short* __restrict__ xbf,
        const float* __restrict__ es, const float* __restrict__ ed,
        int* __restrict__ csr_src, int* __restrict__ rowptr,
        unsigned short* __restrict__ aggx, int N, int NB, int NPAD) {
    __shared__ int cnt[32], excl[32];
    __shared__ int rstart[33];
    __shared__ int ebuf[1152];
    __shared__ int    s_lds[4][2][32];
    __shared__ float2 w_lds[4][2][32];
    const int b = blockIdx.x;
    const int gbase = segbase[b], gend = segbase[b + 1];
    const int sz = gend - gbase;
    const int t = threadIdx.x;
    if (b == 0 && t == 255) rowptr[N] = segbase[NB];
    if (t < 32) cnt[t] = 0;
    __syncthreads();
    const bool fits = (sz <= 1152);
    for (int i = t; i < sz; i += 256) {
        int p = bsorted[gbase + i];
        if (fits) ebuf[i] = p;
        atomicAdd(&cnt[p & BMSK], 1);
    }
    __syncthreads();
    if (t < 32) excl[t] = cnt[t];
    __syncthreads();
    for (int off = 1; off < 32; off <<= 1) {
        int v = (t < 32 && t >= off) ? excl[t - off] : 0;
        __syncthreads();
        if (t < 32) excl[t] += v;
        __syncthreads();
    }
    if (t < 32) {
        int rst = gbase + excl[t] - cnt[t];
        rstart[t] = rst;
        int dst = (b << BSH) + t;
        if (dst < N) rowptr[dst] = rst;
        cnt[t] = excl[t] - cnt[t];           // local running cursor
    } else if (t == 32) {
        rstart[32] = gend;
    }
    __syncthreads();
    if (fits) {
        for (int i = t; i < sz; i += 256) {
            int p = ebuf[i];
            int pos = atomicAdd(&cnt[p & BMSK], 1);
            csr_src[gbase + pos] = p >> BSH;
        }
    } else {
        for (int i = t; i < sz; i += 256) {
            int p = bsorted[gbase + i];
            int pos = atomicAdd(&cnt[p & BMSK], 1);
            csr_src[gbase + pos] = p >> BSH;
        }
    }
    __syncthreads();   // csr_src visible block-wide (waitcnt before barrier)

    // ---- phase B: aggregate the bucket's 32 nodes, 8 per pass ----
    const int wave = t >> 6, lane = t & 63;
    const int g = lane >> 5, c = lane & 31;
#pragma unroll 1
    for (int it = 0; it < 4; ++it) {
        const int local = it * 8 + wave * 2 + g;
        const int node = (b << BSH) + local;
        if (node >= N) continue;
        const int rs = rstart[local], re = rstart[local + 1];
        const float2 edn = *(const float2*)(ed + node * 2);
        float z0 = 0.f, z1 = 0.f;
        float4 p = {0.f, 0.f, 0.f, 0.f}, q = {0.f, 0.f, 0.f, 0.f};
        for (int i = rs; i < re; i += 32) {
            const int cc = min(re - i, 32);
            if (c < cc) {
                int s = csr_src[i + c];
                float2 esv = *(const float2*)(es + s * 2);
                float e0 = esv.x + edn.x; e0 = (e0 > 0.f) ? e0 : 0.2f * e0;
                float e1 = esv.y + edn.y; e1 = (e1 > 0.f) ? e1 : 0.2f * e1;
                float w0 = __expf(e0), w1 = __expf(e1);
                s_lds[wave][g][c] = s;
                w_lds[wave][g][c] = make_float2(w0, w1);
                z0 += w0; z1 += w1;
            }
            // same-wave LDS RAW: compiler inserts lgkmcnt wait
            int k = 0;
            for (; k + 7 < cc; k += 8) {
                int s0 = s_lds[wave][g][k + 0], s1 = s_lds[wave][g][k + 1];
                int s2 = s_lds[wave][g][k + 2], s3 = s_lds[wave][g][k + 3];
                int s4 = s_lds[wave][g][k + 4], s5 = s_lds[wave][g][k + 5];
                int s6 = s_lds[wave][g][k + 6], s7 = s_lds[wave][g][k + 7];
                float2 a0 = w_lds[wave][g][k + 0], a1 = w_lds[wave][g][k + 1];
                float2 a2 = w_lds[wave][g][k + 2], a3 = w_lds[wave][g][k + 3];
                float2 a4 = w_lds[wave][g][k + 4], a5 = w_lds[wave][g][k + 5];
                float2 a6 = w_lds[wave][g][k + 6], a7 = w_lds[wave][g][k + 7];
                ushort4 u0 = *(const ushort4*)(xbf + (size_t)s0 * 128 + c * 4);
                ushort4 u1 = *(const ushort4*)(xbf + (size_t)s1 * 128 + c * 4);
                ushort4 u2 = *(const ushort4*)(xbf + (size_t)s2 * 128 + c * 4);
                ushort4 u3 = *(const ushort4*)(xbf + (size_t)s3 * 128 + c * 4);
                ushort4 u4 = *(const ushort4*)(xbf + (size_t)s4 * 128 + c * 4);
                ushort4 u5 = *(const ushort4*)(xbf + (size_t)s5 * 128 + c * 4);
                ushort4 u6 = *(const ushort4*)(xbf + (size_t)s6 * 128 + c * 4);
                ushort4 u7 = *(const ushort4*)(xbf + (size_t)s7 * 128 + c * 4);
                ACC2(u0, a0, p, q);
                ACC2(u1, a1, p, q);
                ACC2(u2, a2, p, q);
                ACC2(u3, a3, p, q);
                ACC2(u4, a4, p, q);
                ACC2(u5, a5, p, q);
                ACC2(u6, a6, p, q);
                ACC2(u7, a7, p, q);
            }
            for (; k < cc; ++k) {
                int s0 = s_lds[wave][g][k];
                float2 a0 = w_lds[wave][g][k];
                ushort4 u0 = *(const ushort4*)(xbf + (size_t)s0 * 128 + c * 4);
                ACC2(u0, a0, p, q);
            }
        }
#pragma unroll
        for (int off = 16; off >= 1; off >>= 1) {
            z0 += __shfl_xor(z0, off, 64);
            z1 += __shfl_xor(z1, off, 64);
        }
        const float rz0 = 1.f / (z0 + 1e-16f);
        const float rz1 = 1.f / (z1 + 1e-16f);
        ushort4 o;
        o.x = f2bf(p.x * rz0); o.y = f2bf(p.y * rz0);
        o.z = f2bf(p.z * rz0); o.w = f2bf(p.w * rz0);
        *(ushort4*)(aggx + (size_t)node * 128 + c * 4) = o;
        o.x = f2bf(q.x * rz1); o.y = f2bf(q.y * rz1);
        o.z = f2bf(q.z * rz1); o.w = f2bf(q.w * rz1);
        *(ushort4*)(aggx + (size_t)NPAD * 128 + (size_t)node * 128 + c * 4) = o;
    }
}

// ------------------------- fused layer-1 + layer-2 GEMM (32-row tiles) ----
// h1t: 32 rows x 256 cols bf16, stride 512B, XOR-swizzled byte ^= (row&31)<<4
// => stage-2 ds_read_b128 lands 64 lanes on 32 slots (2-way = free).

__global__ __launch_bounds__(256) void gemm12_fused(
        const unsigned short* __restrict__ Abase,
        const unsigned short* __restrict__ B1h0, const unsigned short* __restrict__ B1h1,
        const unsigned short* __restrict__ B2sw,
        const float* __restrict__ b1,
        const float* __restrict__ a_src, const float* __restrict__ a_dst,
        float* __restrict__ es, float* __restrict__ ed,
        unsigned short* __restrict__ C, int N, int NPAD) {
    __shared__ unsigned short h1t[32 * 256];
    __shared__ float lds_ps[4][32];
    __shared__ float lds_pd[4][32];
    const int tid = threadIdx.x;
    const int wave = tid >> 6, lane = tid & 63;
    const int quad = lane >> 4, lo = lane & 15;
    const int n0 = blockIdx.x * 32;
    char* h1b = (char*)h1t;

    // ---- stage 1: h1 tile (32x256) = ELU(A@W1 + b1) -> swizzled LDS ----
    {
        const int head = wave >> 1, wh = wave & 1;
        const unsigned short* A = Abase + (size_t)head * NPAD * 128;
        const bf16x8* Bp = (const bf16x8*)(head ? B1h1 : B1h0);
        bf16x8 bf[4][4];
#pragma unroll
        for (int c = 0; c < 4; ++c)
#pragma unroll
            for (int t = 0; t < 4; ++t)
                bf[c][t] = Bp[((wh * 4 + c) * 4 + t) * 64 + lane];
        f32x4 acc[2][4];
#pragma unroll
        for (int r = 0; r < 2; ++r)
#pragma unroll
            for (int c = 0; c < 4; ++c) acc[r][c] = (f32x4){0.f, 0.f, 0.f, 0.f};
#pragma unroll
        for (int r = 0; r < 2; ++r) {
            const unsigned short* Ar = A + (size_t)(n0 + r * 16 + lo) * 128 + quad * 8;
#pragma unroll
            for (int t = 0; t < 4; ++t) {
                bf16x8 af = *(const bf16x8*)(Ar + t * 32);
#pragma unroll
                for (int c = 0; c < 4; ++c)
                    acc[r][c] = __builtin_amdgcn_mfma_f32_16x16x32_bf16(af, bf[c][t],
                                                                       acc[r][c], 0, 0, 0);
            }
        }
#pragma unroll
        for (int r = 0; r < 2; ++r) {
            int rl = r * 16 + quad * 4;
#pragma unroll
            for (int c = 0; c < 4; ++c) {
                int col = head * 128 + wh * 64 + c * 16 + lo;
                float bv = b1[col];
#pragma unroll
                for (int j = 0; j < 4; ++j) {
                    float v = acc[r][c][j] + bv;
                    v = (v > 0.f) ? v : __expf(v) - 1.f;
                    int row = rl + j;
                    *(unsigned short*)(h1b + row * 512 + ((col * 2) ^ ((row & 31) << 4)))
                        = f2bf(v);
                }
            }
        }
    }
    __syncthreads();

    // ---- stage 2: K=256, FOUT=128 + es2/ed2 epilogue ----
    bf16x8 bf2[2][8];
    {
        const bf16x8* Bp2 = (const bf16x8*)B2sw;
#pragma unroll
        for (int c = 0; c < 2; ++c)
#pragma unroll
            for (int t = 0; t < 8; ++t)
                bf2[c][t] = Bp2[((wave * 2 + c) * 8 + t) * 64 + lane];
    }
    f32x4 acc2[2][2];
#pragma unroll
    for (int r = 0; r < 2; ++r)
#pragma unroll
        for (int c = 0; c < 2; ++c) acc2[r][c] = (f32x4){0.f, 0.f, 0.f, 0.f};
#pragma unroll
    for (int r = 0; r < 2; ++r) {
        const int row = r * 16 + lo;
        const int rsw = (row & 31) << 4;
#pragma unroll
        for (int t = 0; t < 8; ++t) {
            bf16x8 af = *(const bf16x8*)(h1b + row * 512 + (((quad * 8 + t * 32) * 2) ^ rsw));
#pragma unroll
            for (int c = 0; c < 2; ++c)
                acc2[r][c] = __builtin_amdgcn_mfma_f32_16x16x32_bf16(af, bf2[c][t],
                                                                    acc2[r][c], 0, 0, 0);
        }
    }
    const int c0 = wave * 32;
#pragma unroll
    for (int r = 0; r < 2; ++r) {
        int row = n0 + r * 16 + quad * 4;
#pragma unroll
        for (int c = 0; c < 2; ++c) {
            int col = c0 + c * 16 + lo;
#pragma unroll
            for (int j = 0; j < 4; ++j)
                if (row + j < N) C[(size_t)(row + j) * 128 + col] = f2bf(acc2[r][c][j]);
        }
    }
    float asv[2], adv[2];
#pragma unroll
    for (int c = 0; c < 2; ++c) {
        int col = c0 + c * 16 + lo;
        asv[c] = a_src[col];
        adv[c] = a_dst[col];
    }
#pragma unroll
    for (int r = 0; r < 2; ++r) {
#pragma unroll
        for (int j = 0; j < 4; ++j) {
            float ps = 0.f, pd = 0.f;
#pragma unroll
            for (int c = 0; c < 2; ++c) { ps += acc2[r][c][j] * asv[c]; pd += acc2[r][c][j] * adv[c]; }
#pragma unroll
            for (int off = 1; off <= 8; off <<= 1) {
                ps += __shfl_xor(ps, off, 64);
                pd += __shfl_xor(pd, off, 64);
            }
            if (lo == 0) {
                int row_l = r * 16 + quad * 4 + j;
                lds_ps[wave][row_l] = ps;
                lds_pd[wave][row_l] = pd;
            }
        }
    }
    __syncthreads();
    if (tid < 32) {
        int row = tid;
        int n = n0 + row;
        if (n < N) {
            es[n] = lds_ps[0][row] + lds_ps[1][row] + lds_ps[2][row] + lds_ps[3][row];
            ed[n] = lds_pd[0][row] + lds_pd[1][row] + lds_pd[2][row] + lds_pd[3][row];
        }
    }
}

// ------------------------- layer-2 aggregation (2 nodes/wave, inline SM) --

#define ACC1(U_, W_, P_) {                                   \
    P_.x += W_ * bf2f(U_.x); P_.y += W_ * bf2f(U_.y);        \
    P_.z += W_ * bf2f(U_.z); P_.w += W_ * bf2f(U_.w); }

__global__ void gat_agg_h1(const unsigned short* __restrict__ Hpre,
                           const float* __restrict__ es, const float* __restrict__ ed,
                           const int* __restrict__ rowptr, const int* __restrict__ csr_src,
                           const float* __restrict__ bias, unsigned short* __restrict__ out,
                           int N) {
    __shared__ int   s_lds[4][2][32];
    __shared__ float w_lds[4][2][32];
    const int wave = threadIdx.x >> 6, lane = threadIdx.x & 63;
    const int g = lane >> 5, c = lane & 31;
    const int node = (blockIdx.x * 4 + wave) * 2 + g;
    if (node >= N) return;
    const int rs = rowptr[node], re = rowptr[node + 1];
    const float edn = ed[node];

    float z = 0.f;
    float4 p = {0.f, 0.f, 0.f, 0.f};
    for (int i = rs; i < re; i += 32) {
        const int cnt = min(re - i, 32);
        if (c < cnt) {
            int s = csr_src[i + c];
            float e = es[s] + edn;
            e = (e > 0.f) ? e : 0.2f * e;
            float ww = __expf(e);
            s_lds[wave][g][c] = s;
            w_lds[wave][g][c] = ww;
            z += ww;
        }
        // same-wave LDS RAW: compiler inserts lgkmcnt wait
        int k = 0;
        for (; k + 7 < cnt; k += 8) {
            int s0 = s_lds[wave][g][k + 0], s1 = s_lds[wave][g][k + 1];
            int s2 = s_lds[wave][g][k + 2], s3 = s_lds[wave][g][k + 3];
            int s4 = s_lds[wave][g][k + 4], s5 = s_lds[wave][g][k + 5];
            int s6 = s_lds[wave][g][k + 6], s7 = s_lds[wave][g][k + 7];
            float a0 = w_lds[wave][g][k + 0], a1 = w_lds[wave][g][k + 1];
            float a2 = w_lds[wave][g][k + 2], a3 = w_lds[wave][g][k + 3];
            float a4 = w_lds[wave][g][k + 4], a5 = w_lds[wave][g][k + 5];
            float a6 = w_lds[wave][g][k + 6], a7 = w_lds[wave][g][k + 7];
            ushort4 u0 = *(const ushort4*)(Hpre + (size_t)s0 * 128 + c * 4);
            ushort4 u1 = *(const ushort4*)(Hpre + (size_t)s1 * 128 + c * 4);
            ushort4 u2 = *(const ushort4*)(Hpre + (size_t)s2 * 128 + c * 4);
            ushort4 u3 = *(const ushort4*)(Hpre + (size_t)s3 * 128 + c * 4);
            ushort4 u4 = *(const ushort4*)(Hpre + (size_t)s4 * 128 + c * 4);
            ushort4 u5 = *(const ushort4*)(Hpre + (size_t)s5 * 128 + c * 4);
            ushort4 u6 = *(const ushort4*)(Hpre + (size_t)s6 * 128 + c * 4);
            ushort4 u7 = *(const ushort4*)(Hpre + (size_t)s7 * 128 + c * 4);
            ACC1(u0, a0, p);
            ACC1(u1, a1, p);
            ACC1(u2, a2, p);
            ACC1(u3, a3, p);
            ACC1(u4, a4, p);
            ACC1(u5, a5, p);
            ACC1(u6, a6, p);
            ACC1(u7, a7, p);
        }
        for (; k < cnt; ++k) {
            int s0 = s_lds[wave][g][k];
            float a0 = w_lds[wave][g][k];
            ushort4 u0 = *(const ushort4*)(Hpre + (size_t)s0 * 128 + c * 4);
            ACC1(u0, a0, p);
        }
    }
#pragma unroll
    for (int off = 16; off >= 1; off >>= 1) z += __shfl_xor(z, off, 64);
    const float rz = 1.f / (z + 1e-16f);
    float4 bv = ((const float4*)bias)[c];
    float ox = p.x * rz + bv.x, oy = p.y * rz + bv.y;
    float oz = p.z * rz + bv.z, ow = p.w * rz + bv.w;
    ox = (ox > 0.f) ? ox : __expf(ox) - 1.f;
    oy = (oy > 0.f) ? oy : __expf(oy) - 1.f;
    oz = (oz > 0.f) ? oz : __expf(oz) - 1.f;
    ow = (ow > 0.f) ? ow : __expf(ow) - 1.f;
    ushort4 o;
    o.x = f2bf(ox); o.y = f2bf(oy); o.z = f2bf(oz); o.w = f2bf(ow);
    *(ushort4*)(out + (size_t)node * 128 + c * 4) = o;
}

// ------------------------- global mean pool (chunk-parallel) --------------

__global__ __launch_bounds__(256) void pool_partial(const unsigned short* __restrict__ h2,
                                                    const int* __restrict__ batch,
                                                    float* __restrict__ xsum,
                                                    int* __restrict__ cnt, int N) {
    const int base = blockIdx.x * PCHUNK;
    const int rg = threadIdx.x >> 6;
    const int c2 = threadIdx.x & 63;
    float ax = 0.f, ay = 0.f;
    int gcur = -1, run = 0;
    for (int r = rg; r < PCHUNK; r += 4) {
        int i = base + r;
        if (i >= N) break;
        int g = batch[i];
        if (g != gcur) {
            if (gcur >= 0) {
                atomicAdd(&xsum[gcur * 128 + c2 * 2 + 0], ax);
                atomicAdd(&xsum[gcur * 128 + c2 * 2 + 1], ay);
                if (c2 == 0) atomicAdd(&cnt[gcur], run);
            }
            gcur = g; ax = 0.f; ay = 0.f; run = 0;
        }
        ushort2 u = *(const ushort2*)(h2 + (size_t)i * 128 + c2 * 2);
        ax += bf2f(u.x); ay += bf2f(u.y);
        run += 1;
    }
    if (gcur >= 0) {
        atomicAdd(&xsum[gcur * 128 + c2 * 2 + 0], ax);
        atomicAdd(&xsum[gcur * 128 + c2 * 2 + 1], ay);
        if (c2 == 0) atomicAdd(&cnt[gcur], run);
    }
}

// ------------------------- policy / value heads ---------------------------

__global__ void head_kernel(const float* __restrict__ xsum, const int* __restrict__ cnt,
                            const float* __restrict__ Wp, const float* __restrict__ bp,
                            const float* __restrict__ Wv, const float* __restrict__ bv,
                            float* __restrict__ out) {
    int g = blockIdx.x, t = threadIdx.x;  // 64 threads
    __shared__ float p[128];
    float inv = 1.f / fmaxf((float)cnt[g], 1.f);
    p[t] = xsum[g * 128 + t] * inv;
    p[t + 64] = xsum[g * 128 + t + 64] * inv;
    __syncthreads();
    if (t < 32) {
        float acc = bp[t];
        for (int k = 0; k < 128; ++k) acc += p[k] * Wp[k * 32 + t];
        out[g * 32 + t] = acc;
    } else if (t == 32) {
        float acc = bv[0];
        for (int k = 0; k < 128; ++k) acc += p[k] * Wv[k];
        out[64 * 32 + g] = acc;
    }
}

// ---------------------------------------------------------------------------

extern "C" void kernel_launch(void* const* d_in, const int* in_sizes, int n_in,
                              void* d_out, int out_size, void* d_ws, size_t ws_size,
                              hipStream_t stream) {
    const float* x      = (const float*)d_in[0];
    const int*   ei     = (const int*)d_in[1];
    const int*   batch  = (const int*)d_in[2];
    const float* W1     = (const float*)d_in[3];
    const float* a_src1 = (const float*)d_in[4];
    const float* a_dst1 = (const float*)d_in[5];
    const float* b1     = (const float*)d_in[6];
    const float* W2     = (const float*)d_in[7];
    const float* a_src2 = (const float*)d_in[8];
    const float* a_dst2 = (const float*)d_in[9];
    const float* b2     = (const float*)d_in[10];
    const float* Wp     = (const float*)d_in[11];
    const float* bp     = (const float*)d_in[12];
    const float* Wv     = (const float*)d_in[13];
    const float* bv     = (const float*)d_in[14];

    const int N  = in_sizes[0] / 128;
    const int E  = in_sizes[1] / 2;
    const int ET = E + N;
    const int NPAD = ((N + 63) / 64) * 64;
    const int NBLK32 = NPAD / 32;
    const int PBLK = (N + PCHUNK - 1) / PCHUNK;
    const int NB = (N + BMSK) >> BSH;               // 32-node buckets
    const int CHUNK = (ET + NBLK_H - 1) / NBLK_H;
    const int M = NB * NBLK_H;
    const int TILESH = (M + 1023) / 1024;           // <=256 (N<=65536 -> 245)
    const int AB = (N + 3) / 4;
    const int GB = (N + 7) / 8;

    char* ws = (char*)d_ws;
    size_t off = 0;
    auto alloc = [&](size_t bytes) -> void* {
        void* p = ws + off;
        off = (off + bytes + 255) & ~(size_t)255;
        return p;
    };
    unsigned short* xbf   = (unsigned short*)alloc((size_t)NPAD * 128 * 2);
    unsigned short* aggx  = (unsigned short*)alloc((size_t)2 * NPAD * 128 * 2);
    unsigned short* h2pre = (unsigned short*)alloc((size_t)NPAD * 128 * 2);
    unsigned short* h2bf  = (unsigned short*)alloc((size_t)N * 128 * 2);
    unsigned short* w1h0  = (unsigned short*)alloc((size_t)128 * 128 * 2);
    unsigned short* w1h1  = (unsigned short*)alloc((size_t)128 * 128 * 2);
    unsigned short* w2sw  = (unsigned short*)alloc((size_t)256 * 128 * 2);
    float* v1s = (float*)alloc(256 * 4);
    float* v1d = (float*)alloc(256 * 4);
    float* es1 = (float*)alloc((size_t)N * 2 * 4);
    float* ed1 = (float*)alloc((size_t)N * 2 * 4);
    float* es2 = (float*)alloc((size_t)N * 4);
    float* ed2 = (float*)alloc((size_t)N * 4);
    // contiguous zero region: xsum | cnt
    const int ZINTS = 64 * 128 + 64;
    int*   zbase  = (int*)alloc(((size_t)ZINTS + 8) * 4);
    float* xsum   = (float*)zbase;
    int*   cnt    = (int*)(xsum + 64 * 128);
    int*    rowptr    = (int*)alloc((size_t)(N + 1) * 4);
    int*    hist      = (int*)alloc((size_t)M * 4);
    int*    segbase   = (int*)alloc((size_t)(NB + 1) * 4);
    int*    bsorted   = (int*)alloc((size_t)ET * 4);
    int*    csrsrc    = (int*)alloc((size_t)ET * 4);
    int*    tsum      = (int*)alloc(256 * 4);
    const int zn4 = (ZINTS + 3) / 4;
    const int ZB = (zn4 + 255) / 256;

    // 1. init: swizzles + v1 + zero + edge histogram
    init_kernel<<<33 + ZB + NBLK_H, 256, 0, stream>>>(W1, W2, a_src1, a_dst1,
                                                      w1h0, w1h1, w2sw, v1s, v1d,
                                                      zbase, zn4, ZB,
                                                      ei, hist, E, ET, CHUNK, NB);
    // 2. hist tile-scan + attn1 coefs + x cast
    scan_attn1<<<TILESH + AB, 256, 0, stream>>>(hist, tsum, M, TILESH,
                                                x, v1s, v1d, es1, ed1, xbf, N);
    // 3. partition (folds global scan; blk0 emits segbase)
    part_kernel<<<NBLK_H, 256, 0, stream>>>(ei, hist, tsum, bsorted, segbase,
                                            E, ET, CHUNK, NB, TILESH);
    // 4. fused bucket counting sort + layer-1 aggregation
    bucket_agg<<<NB, 256, 0, stream>>>(bsorted, segbase, xbf, es1, ed1,
                                       csrsrc, rowptr, aggx, N, NB, NPAD);
    // 5. fused layer-1 + layer-2 GEMM, 32-row tiles (+es2/ed2 epilogue)
    gemm12_fused<<<NBLK32, 256, 0, stream>>>(aggx, w1h0, w1h1, w2sw, b1,
                                             a_src2, a_dst2, es2, ed2, h2pre, N, NPAD);
    // 6. layer-2 aggregation (2 nodes/wave, inline softmax, 8-deep)
    gat_agg_h1<<<GB, 256, 0, stream>>>(h2pre, es2, ed2, rowptr, csrsrc, b2, h2bf, N);
    // 7/8. pool + heads
    pool_partial<<<PBLK, 256, 0, stream>>>(h2bf, batch, xsum, cnt, N);
    head_kernel<<<64, 64, 0, stream>>>(xsum, cnt, Wp, bp, Wv, bv, (float*)d_out);
}

// Round 13
// 271.627 us; speedup vs baseline: 1.0271x; 1.0271x over previous
//
#include <hip/hip_runtime.h>
#include <hip/hip_bf16.h>
#include <cstdint>

// ---------------------------------------------------------------------------
// GraphRLAgent: 2-layer GAT (heads=2 then 1) + global mean pool + 2 heads.
// Round 30: REVERT to R28 (274.4us, session best). R29's bucket+agg fusion
// regressed (279.0: fused kernel 53.7us @ 27.6% occ -- serial sort phase in
// front of the gather + lower agg occupancy cost more than the saved launch
// gap; same failure family as R23). Final structure: 9 regular launches,
// 2-nodes-per-wave inline-softmax aggs, 32-row swizzled gemm12.
// Remaining budget: ~42us harness fill + ~60us launch gaps (coop sync dead
// per R25) + ~170us kernels at their concurrency-limited gather floor.
// ---------------------------------------------------------------------------

typedef __attribute__((ext_vector_type(8))) short bf16x8;
typedef __attribute__((ext_vector_type(4))) float f32x4;

#define NBLK_H 160   // edge chunks for hist/partition passes
#define BSH 6        // bucket shift: 64 nodes per bucket
#define BMSK 63
#define PCHUNK 256

__device__ __forceinline__ float wave_sum(float v) {
#pragma unroll
    for (int off = 32; off >= 1; off >>= 1) v += __shfl_xor(v, off, 64);
    return v;
}

__device__ __forceinline__ unsigned short f2bf(float f) {
    union { float f; uint32_t u; } c; c.f = f;
    uint32_t u = c.u;
    return (unsigned short)((u + 0x7fffu + ((u >> 16) & 1u)) >> 16);
}

__device__ __forceinline__ float bf2f(unsigned short u) {
    union { uint32_t u; float f; } c; c.u = ((uint32_t)u) << 16;
    return c.f;
}

// ------------------------- B swizzle body (ldW/colOff aware) --------------

template <int K, int FOUT>
__device__ __forceinline__ void swizzle_body(const float* __restrict__ W, int ldW, int colOff,
                                             unsigned short* __restrict__ Bsw, int tid) {
    constexpr int CPW = FOUT / 4, NCT = CPW / 16, KST = K / 32;
    if (tid >= K * FOUT / 8) return;
    int lane = tid & 63;
    int rest = tid >> 6;
    int t = rest % KST; rest /= KST;
    int c = rest % NCT; rest /= NCT;
    int cg_ = rest;
    int quad = lane >> 4, lo = lane & 15;
    int col = colOff + cg_ * CPW + c * 16 + lo;
    unsigned short v[8];
#pragma unroll
    for (int j = 0; j < 8; ++j)
        v[j] = f2bf(W[(t * 32 + quad * 8 + j) * ldW + col]);
    ushort4* dst = (ushort4*)(Bsw + (size_t)tid * 8);
    ushort4 o0, o1;
    o0.x = v[0]; o0.y = v[1]; o0.z = v[2]; o0.w = v[3];
    o1.x = v[4]; o1.y = v[5]; o1.z = v[6]; o1.w = v[7];
    dst[0] = o0; dst[1] = o1;
}

// ------------------------- init: zero + swizzles + v1 + edge hist ---------

__global__ __launch_bounds__(256) void init_kernel(
        const float* __restrict__ W1, const float* __restrict__ W2,
        const float* __restrict__ a_src1, const float* __restrict__ a_dst1,
        unsigned short* __restrict__ B1h0, unsigned short* __restrict__ B1h1,
        unsigned short* __restrict__ B2,
        float* __restrict__ v1s, float* __restrict__ v1d,
        int* __restrict__ zbase, int zn4, int ZB,
        const int* __restrict__ ei, int* __restrict__ hist,
        int E, int ET, int CHUNK, int NB) {
    __shared__ int bins[1024];
    int b = blockIdx.x;
    if (b < 8)        swizzle_body<128, 128>(W1, 256, 0,   B1h0, b * 256 + threadIdx.x);
    else if (b < 16)  swizzle_body<128, 128>(W1, 256, 128, B1h1, (b - 8) * 256 + threadIdx.x);
    else if (b < 32)  swizzle_body<256, 128>(W2, 128, 0,   B2, (b - 16) * 256 + threadIdx.x);
    else if (b == 32) {
        int t = threadIdx.x, h = t >> 7, k = t & 127;
        float vs = 0.f, vd = 0.f;
        for (int c = 0; c < 128; ++c) {
            float w = W1[k * 256 + h * 128 + c];
            vs += w * a_src1[h * 128 + c];
            vd += w * a_dst1[h * 128 + c];
        }
        v1s[h * 128 + k] = vs;
        v1d[h * 128 + k] = vd;
    } else if (b < 33 + ZB) {
        int i = (b - 33) * 256 + threadIdx.x;
        if (i < zn4) ((int4*)zbase)[i] = make_int4(0, 0, 0, 0);
    } else {
        const int blk = b - 33 - ZB;
        for (int t = threadIdx.x; t < NB; t += 256) bins[t] = 0;
        __syncthreads();
        const int start = blk * CHUNK, end = min(ET, start + CHUNK);
        for (int i = start + threadIdx.x; i < end; i += 256) {
            int dst = (i < E) ? ei[E + i] : (i - E);
            atomicAdd(&bins[dst >> BSH], 1);
        }
        __syncthreads();
        for (int t = threadIdx.x; t < NB; t += 256) hist[t * NBLK_H + blk] = bins[t];
    }
}

// ------------------------- scan_tiles + attn1_cast (fused launch) ---------

__global__ __launch_bounds__(256) void scan_attn1(
        int* __restrict__ hist, int* __restrict__ tsum, int M, int TILESH,
        const float* __restrict__ x, const float* __restrict__ v1s,
        const float* __restrict__ v1d, float* __restrict__ es1,
        float* __restrict__ ed1, unsigned short* __restrict__ xbf, int N) {
    __shared__ int buf[256];
    if ((int)blockIdx.x < TILESH) {
        const int t = threadIdx.x;
        const int base = blockIdx.x * 1024 + t * 4;
        int v[4]; int s = 0;
#pragma unroll
        for (int k = 0; k < 4; ++k) { v[k] = (base + k < M) ? hist[base + k] : 0; s += v[k]; }
        buf[t] = s;
        __syncthreads();
#pragma unroll
        for (int off = 1; off < 256; off <<= 1) {
            int xx = (t >= off) ? buf[t - off] : 0;
            __syncthreads();
            buf[t] += xx;
            __syncthreads();
        }
        int run = buf[t] - s;
#pragma unroll
        for (int k = 0; k < 4; ++k) {
            if (base + k < M) hist[base + k] = run;
            run += v[k];
        }
        if (t == 255) tsum[blockIdx.x] = buf[255];
        return;
    }
    int bid = blockIdx.x - TILESH;
    int wid = (bid * 256 + threadIdx.x) >> 6;
    int lane = threadIdx.x & 63;
    if (wid >= N) return;
    float2 xv = *(const float2*)(x + (size_t)wid * 128 + lane * 2);
    float p0s = xv.x * v1s[lane * 2] + xv.y * v1s[lane * 2 + 1];
    float p1s = xv.x * v1s[128 + lane * 2] + xv.y * v1s[128 + lane * 2 + 1];
    float p0d = xv.x * v1d[lane * 2] + xv.y * v1d[lane * 2 + 1];
    float p1d = xv.x * v1d[128 + lane * 2] + xv.y * v1d[128 + lane * 2 + 1];
    p0s = wave_sum(p0s); p1s = wave_sum(p1s);
    p0d = wave_sum(p0d); p1d = wave_sum(p1d);
    if (lane == 0) {
        es1[wid * 2] = p0s; es1[wid * 2 + 1] = p1s;
        ed1[wid * 2] = p0d; ed1[wid * 2 + 1] = p1d;
    }
    ushort2 o; o.x = f2bf(xv.x); o.y = f2bf(xv.y);
    *(ushort2*)(xbf + (size_t)wid * 128 + lane * 2) = o;
}

// ------------------------- partition (folds global scan) ------------------

__global__ __launch_bounds__(256) void part_kernel(const int* __restrict__ ei,
                                                   const int* __restrict__ hist,
                                                   const int* __restrict__ tsum,
                                                   int* __restrict__ bsorted,
                                                   int* __restrict__ segbase,
                                                   int E, int ET, int CHUNK, int NB, int T) {
    __shared__ int sb[256];
    __shared__ int scur[1024];
    const int t = threadIdx.x;
    sb[t] = (t < T) ? tsum[t] : 0;
    __syncthreads();
#pragma unroll
    for (int off = 1; off < 256; off <<= 1) {
        int v = (t >= off) ? sb[t - off] : 0;
        __syncthreads();
        sb[t] += v;
        __syncthreads();
    }
    const int blk = blockIdx.x;
    for (int b = t; b < NB; b += 256) {
        int idx = b * NBLK_H + blk;
        int tile = idx >> 10;
        int v = hist[idx] + (tile ? sb[tile - 1] : 0);
        scur[b] = v;
        if (blk == 0) segbase[b] = v;
    }
    if (blk == 0 && t == 0) segbase[NB] = sb[T - 1];
    __syncthreads();
    const int start = blk * CHUNK, end = min(ET, start + CHUNK);
    for (int i = start + t; i < end; i += 256) {
        int dst = (i < E) ? ei[E + i] : (i - E);
        int src = (i < E) ? ei[i] : dst;
        int pos = atomicAdd(&scur[dst >> BSH], 1);
        bsorted[pos] = (src << BSH) | (dst & BMSK);
    }
}

// ------------------------- bucket counting sort ---------------------------

__global__ __launch_bounds__(256) void bucket_kernel(const int* __restrict__ bsorted,
                                                     const int* __restrict__ segbase,
                                                     int* __restrict__ csr_src,
                                                     int* __restrict__ rowptr,
                                                     int N, int NB) {
    __shared__ int cnt[64];
    __shared__ int excl[64];
    __shared__ int ebuf[2304];
    const int b = blockIdx.x;
    const int gbase = segbase[b];
    const int gend  = segbase[b + 1];
    const int sz = gend - gbase;
    const int t = threadIdx.x;
    if (b == 0 && t == 255) rowptr[N] = segbase[NB];
    if (t < 64) cnt[t] = 0;
    __syncthreads();
    const bool fits = (sz <= 2304);
    if (fits) {
        for (int i = t; i < sz; i += 256) {
            int p = bsorted[gbase + i];
            ebuf[i] = p;
            atomicAdd(&cnt[p & BMSK], 1);
        }
    } else {
        for (int i = t; i < sz; i += 256) {
            int p = bsorted[gbase + i];
            atomicAdd(&cnt[p & BMSK], 1);
        }
    }
    __syncthreads();
    if (t < 64) excl[t] = cnt[t];
    __syncthreads();
    for (int off = 1; off < 64; off <<= 1) {
        int v = (t < 64 && t >= off) ? excl[t - off] : 0;
        __syncthreads();
        if (t < 64) excl[t] += v;
        __syncthreads();
    }
    if (t < 64) {
        int dst = (b << BSH) + t;
        if (dst < N) rowptr[dst] = gbase + excl[t] - cnt[t];
    }
    __syncthreads();
    if (t < 64) cnt[t] = excl[t] - cnt[t];  // repurpose as running cursor
    __syncthreads();
    if (fits) {
        for (int i = t; i < sz; i += 256) {
            int p = ebuf[i];
            int pos = atomicAdd(&cnt[p & BMSK], 1);
            csr_src[gbase + pos] = p >> BSH;
        }
    } else {
        for (int i = t; i < sz; i += 256) {
            int p = bsorted[gbase + i];
            int pos = atomicAdd(&cnt[p & BMSK], 1);
            csr_src[gbase + pos] = p >> BSH;
        }
    }
}

// ------------------------- layer-1 aggregation (2 nodes/wave, inline SM) --
// 32-lane group per node: phase-1 lane c loads csr_src[i+c], gathers float2
// es[s] (both heads), computes w0/w1 -> LDS; z0/z1 accumulate per-lane then
// 5-shuffle group reduce. Phase-2: 8 full-row loads in flight per group;
// each lane owns features c*4..c*4+3 and applies BOTH heads' weights.
// NOTE: macro params must not be named x/y/z/w (token substitution).

#define ACC2(U_, WW_, P_, Q_) { float v_;                              \
    v_ = bf2f(U_.x); P_.x += WW_.x * v_; Q_.x += WW_.y * v_;           \
    v_ = bf2f(U_.y); P_.y += WW_.x * v_; Q_.y += WW_.y * v_;           \
    v_ = bf2f(U_.z); P_.z += WW_.x * v_; Q_.z += WW_.y * v_;           \
    v_ = bf2f(U_.w); P_.w += WW_.x * v_; Q_.w += WW_.y * v_; }

__global__ void gat_agg_x(const unsigned short* __restrict__ xbf,
                          const float* __restrict__ es, const float* __restrict__ ed,
                          const int* __restrict__ rowptr, const int* __restrict__ csr_src,
                          unsigned short* __restrict__ aggx, int N, int NPAD) {
    __shared__ int    s_lds[4][2][32];
    __shared__ float2 w_lds[4][2][32];
    const int wave = threadIdx.x >> 6, lane = threadIdx.x & 63;
    const int g = lane >> 5, c = lane & 31;
    const int node = (blockIdx.x * 4 + wave) * 2 + g;
    if (node >= N) return;
    const int rs = rowptr[node], re = rowptr[node + 1];
    const float2 edn = *(const float2*)(ed + node * 2);

    float z0 = 0.f, z1 = 0.f;
    float4 p = {0.f, 0.f, 0.f, 0.f}, q = {0.f, 0.f, 0.f, 0.f};
    for (int i = rs; i < re; i += 32) {
        const int cnt = min(re - i, 32);
        if (c < cnt) {
            int s = csr_src[i + c];
            float2 esv = *(const float2*)(es + s * 2);
            float e0 = esv.x + edn.x; e0 = (e0 > 0.f) ? e0 : 0.2f * e0;
            float e1 = esv.y + edn.y; e1 = (e1 > 0.f) ? e1 : 0.2f * e1;
            float w0 = __expf(e0), w1 = __expf(e1);
            s_lds[wave][g][c] = s;
            w_lds[wave][g][c] = make_float2(w0, w1);
            z0 += w0; z1 += w1;
        }
        // same-wave LDS RAW: compiler inserts lgkmcnt wait
        int k = 0;
        for (; k + 7 < cnt; k += 8) {
            int s0 = s_lds[wave][g][k + 0], s1 = s_lds[wave][g][k + 1];
            int s2 = s_lds[wave][g][k + 2], s3 = s_lds[wave][g][k + 3];
            int s4 = s_lds[wave][g][k + 4], s5 = s_lds[wave][g][k + 5];
            int s6 = s_lds[wave][g][k + 6], s7 = s_lds[wave][g][k + 7];
            float2 a0 = w_lds[wave][g][k + 0], a1 = w_lds[wave][g][k + 1];
            float2 a2 = w_lds[wave][g][k + 2], a3 = w_lds[wave][g][k + 3];
            float2 a4 = w_lds[wave][g][k + 4], a5 = w_lds[wave][g][k + 5];
            float2 a6 = w_lds[wave][g][k + 6], a7 = w_lds[wave][g][k + 7];
            ushort4 u0 = *(const ushort4*)(xbf + (size_t)s0 * 128 + c * 4);
            ushort4 u1 = *(const ushort4*)(xbf + (size_t)s1 * 128 + c * 4);
            ushort4 u2 = *(const ushort4*)(xbf + (size_t)s2 * 128 + c * 4);
            ushort4 u3 = *(const ushort4*)(xbf + (size_t)s3 * 128 + c * 4);
            ushort4 u4 = *(const ushort4*)(xbf + (size_t)s4 * 128 + c * 4);
            ushort4 u5 = *(const ushort4*)(xbf + (size_t)s5 * 128 + c * 4);
            ushort4 u6 = *(const ushort4*)(xbf + (size_t)s6 * 128 + c * 4);
            ushort4 u7 = *(const ushort4*)(xbf + (size_t)s7 * 128 + c * 4);
            ACC2(u0, a0, p, q);
            ACC2(u1, a1, p, q);
            ACC2(u2, a2, p, q);
            ACC2(u3, a3, p, q);
            ACC2(u4, a4, p, q);
            ACC2(u5, a5, p, q);
            ACC2(u6, a6, p, q);
            ACC2(u7, a7, p, q);
        }
        for (; k < cnt; ++k) {
            int s0 = s_lds[wave][g][k];
            float2 a0 = w_lds[wave][g][k];
            ushort4 u0 = *(const ushort4*)(xbf + (size_t)s0 * 128 + c * 4);
            ACC2(u0, a0, p, q);
        }
    }
    // group (32-lane) reduction of z0/z1: xor offsets stay within the half
#pragma unroll
    for (int off = 16; off >= 1; off >>= 1) {
        z0 += __shfl_xor(z0, off, 64);
        z1 += __shfl_xor(z1, off, 64);
    }
    const float rz0 = 1.f / (z0 + 1e-16f);
    const float rz1 = 1.f / (z1 + 1e-16f);
    ushort4 o;
    o.x = f2bf(p.x * rz0); o.y = f2bf(p.y * rz0);
    o.z = f2bf(p.z * rz0); o.w = f2bf(p.w * rz0);
    *(ushort4*)(aggx + (size_t)node * 128 + c * 4) = o;
    o.x = f2bf(q.x * rz1); o.y = f2bf(q.y * rz1);
    o.z = f2bf(q.z * rz1); o.w = f2bf(q.w * rz1);
    *(ushort4*)(aggx + (size_t)NPAD * 128 + (size_t)node * 128 + c * 4) = o;
}

// ------------------------- fused layer-1 + layer-2 GEMM (32-row tiles) ----
// h1t: 32 rows x 256 cols bf16, stride 512B, XOR-swizzled byte ^= (row&31)<<4
// => stage-2 ds_read_b128 lands 64 lanes on 32 slots (2-way = free).

__global__ __launch_bounds__(256) void gemm12_fused(
        const unsigned short* __restrict__ Abase,
        const unsigned short* __restrict__ B1h0, const unsigned short* __restrict__ B1h1,
        const unsigned short* __restrict__ B2sw,
        const float* __restrict__ b1,
        const float* __restrict__ a_src, const float* __restrict__ a_dst,
        float* __restrict__ es, float* __restrict__ ed,
        unsigned short* __restrict__ C, int N, int NPAD) {
    __shared__ unsigned short h1t[32 * 256];
    __shared__ float lds_ps[4][32];
    __shared__ float lds_pd[4][32];
    const int tid = threadIdx.x;
    const int wave = tid >> 6, lane = tid & 63;
    const int quad = lane >> 4, lo = lane & 15;
    const int n0 = blockIdx.x * 32;
    char* h1b = (char*)h1t;

    // ---- stage 1: h1 tile (32x256) = ELU(A@W1 + b1) -> swizzled LDS ----
    {
        const int head = wave >> 1, wh = wave & 1;
        const unsigned short* A = Abase + (size_t)head * NPAD * 128;
        const bf16x8* Bp = (const bf16x8*)(head ? B1h1 : B1h0);
        bf16x8 bf[4][4];
#pragma unroll
        for (int c = 0; c < 4; ++c)
#pragma unroll
            for (int t = 0; t < 4; ++t)
                bf[c][t] = Bp[((wh * 4 + c) * 4 + t) * 64 + lane];
        f32x4 acc[2][4];
#pragma unroll
        for (int r = 0; r < 2; ++r)
#pragma unroll
            for (int c = 0; c < 4; ++c) acc[r][c] = (f32x4){0.f, 0.f, 0.f, 0.f};
#pragma unroll
        for (int r = 0; r < 2; ++r) {
            const unsigned short* Ar = A + (size_t)(n0 + r * 16 + lo) * 128 + quad * 8;
#pragma unroll
            for (int t = 0; t < 4; ++t) {
                bf16x8 af = *(const bf16x8*)(Ar + t * 32);
#pragma unroll
                for (int c = 0; c < 4; ++c)
                    acc[r][c] = __builtin_amdgcn_mfma_f32_16x16x32_bf16(af, bf[c][t],
                                                                       acc[r][c], 0, 0, 0);
            }
        }
#pragma unroll
        for (int r = 0; r < 2; ++r) {
            int rl = r * 16 + quad * 4;
#pragma unroll
            for (int c = 0; c < 4; ++c) {
                int col = head * 128 + wh * 64 + c * 16 + lo;
                float bv = b1[col];
#pragma unroll
                for (int j = 0; j < 4; ++j) {
                    float v = acc[r][c][j] + bv;
                    v = (v > 0.f) ? v : __expf(v) - 1.f;
                    int row = rl + j;
                    *(unsigned short*)(h1b + row * 512 + ((col * 2) ^ ((row & 31) << 4)))
                        = f2bf(v);
                }
            }
        }
    }
    __syncthreads();

    // ---- stage 2: K=256, FOUT=128 + es2/ed2 epilogue ----
    bf16x8 bf2[2][8];
    {
        const bf16x8* Bp2 = (const bf16x8*)B2sw;
#pragma unroll
        for (int c = 0; c < 2; ++c)
#pragma unroll
            for (int t = 0; t < 8; ++t)
                bf2[c][t] = Bp2[((wave * 2 + c) * 8 + t) * 64 + lane];
    }
    f32x4 acc2[2][2];
#pragma unroll
    for (int r = 0; r < 2; ++r)
#pragma unroll
        for (int c = 0; c < 2; ++c) acc2[r][c] = (f32x4){0.f, 0.f, 0.f, 0.f};
#pragma unroll
    for (int r = 0; r < 2; ++r) {
        const int row = r * 16 + lo;
        const int rsw = (row & 31) << 4;
#pragma unroll
        for (int t = 0; t < 8; ++t) {
            bf16x8 af = *(const bf16x8*)(h1b + row * 512 + (((quad * 8 + t * 32) * 2) ^ rsw));
#pragma unroll
            for (int c = 0; c < 2; ++c)
                acc2[r][c] = __builtin_amdgcn_mfma_f32_16x16x32_bf16(af, bf2[c][t],
                                                                    acc2[r][c], 0, 0, 0);
        }
    }
    const int c0 = wave * 32;
#pragma unroll
    for (int r = 0; r < 2; ++r) {
        int row = n0 + r * 16 + quad * 4;
#pragma unroll
        for (int c = 0; c < 2; ++c) {
            int col = c0 + c * 16 + lo;
#pragma unroll
            for (int j = 0; j < 4; ++j)
                if (row + j < N) C[(size_t)(row + j) * 128 + col] = f2bf(acc2[r][c][j]);
        }
    }
    float asv[2], adv[2];
#pragma unroll
    for (int c = 0; c < 2; ++c) {
        int col = c0 + c * 16 + lo;
        asv[c] = a_src[col];
        adv[c] = a_dst[col];
    }
#pragma unroll
    for (int r = 0; r < 2; ++r) {
#pragma unroll
        for (int j = 0; j < 4; ++j) {
            float ps = 0.f, pd = 0.f;
#pragma unroll
            for (int c = 0; c < 2; ++c) { ps += acc2[r][c][j] * asv[c]; pd += acc2[r][c][j] * adv[c]; }
#pragma unroll
            for (int off = 1; off <= 8; off <<= 1) {
                ps += __shfl_xor(ps, off, 64);
                pd += __shfl_xor(pd, off, 64);
            }
            if (lo == 0) {
                int row_l = r * 16 + quad * 4 + j;
                lds_ps[wave][row_l] = ps;
                lds_pd[wave][row_l] = pd;
            }
        }
    }
    __syncthreads();
    if (tid < 32) {
        int row = tid;
        int n = n0 + row;
        if (n < N) {
            es[n] = lds_ps[0][row] + lds_ps[1][row] + lds_ps[2][row] + lds_ps[3][row];
            ed[n] = lds_pd[0][row] + lds_pd[1][row] + lds_pd[2][row] + lds_pd[3][row];
        }
    }
}

// ------------------------- layer-2 aggregation (2 nodes/wave, inline SM) --

#define ACC1(U_, W_, P_) {                                   \
    P_.x += W_ * bf2f(U_.x); P_.y += W_ * bf2f(U_.y);        \
    P_.z += W_ * bf2f(U_.z); P_.w += W_ * bf2f(U_.w); }

__global__ void gat_agg_h1(const unsigned short* __restrict__ Hpre,
                           const float* __restrict__ es, const float* __restrict__ ed,
                           const int* __restrict__ rowptr, const int* __restrict__ csr_src,
                           const float* __restrict__ bias, unsigned short* __restrict__ out,
                           int N) {
    __shared__ int   s_lds[4][2][32];
    __shared__ float w_lds[4][2][32];
    const int wave = threadIdx.x >> 6, lane = threadIdx.x & 63;
    const int g = lane >> 5, c = lane & 31;
    const int node = (blockIdx.x * 4 + wave) * 2 + g;
    if (node >= N) return;
    const int rs = rowptr[node], re = rowptr[node + 1];
    const float edn = ed[node];

    float z = 0.f;
    float4 p = {0.f, 0.f, 0.f, 0.f};
    for (int i = rs; i < re; i += 32) {
        const int cnt = min(re - i, 32);
        if (c < cnt) {
            int s = csr_src[i + c];
            float e = es[s] + edn;
            e = (e > 0.f) ? e : 0.2f * e;
            float ww = __expf(e);
            s_lds[wave][g][c] = s;
            w_lds[wave][g][c] = ww;
            z += ww;
        }
        // same-wave LDS RAW: compiler inserts lgkmcnt wait
        int k = 0;
        for (; k + 7 < cnt; k += 8) {
            int s0 = s_lds[wave][g][k + 0], s1 = s_lds[wave][g][k + 1];
            int s2 = s_lds[wave][g][k + 2], s3 = s_lds[wave][g][k + 3];
            int s4 = s_lds[wave][g][k + 4], s5 = s_lds[wave][g][k + 5];
            int s6 = s_lds[wave][g][k + 6], s7 = s_lds[wave][g][k + 7];
            float a0 = w_lds[wave][g][k + 0], a1 = w_lds[wave][g][k + 1];
            float a2 = w_lds[wave][g][k + 2], a3 = w_lds[wave][g][k + 3];
            float a4 = w_lds[wave][g][k + 4], a5 = w_lds[wave][g][k + 5];
            float a6 = w_lds[wave][g][k + 6], a7 = w_lds[wave][g][k + 7];
            ushort4 u0 = *(const ushort4*)(Hpre + (size_t)s0 * 128 + c * 4);
            ushort4 u1 = *(const ushort4*)(Hpre + (size_t)s1 * 128 + c * 4);
            ushort4 u2 = *(const ushort4*)(Hpre + (size_t)s2 * 128 + c * 4);
            ushort4 u3 = *(const ushort4*)(Hpre + (size_t)s3 * 128 + c * 4);
            ushort4 u4 = *(const ushort4*)(Hpre + (size_t)s4 * 128 + c * 4);
            ushort4 u5 = *(const ushort4*)(Hpre + (size_t)s5 * 128 + c * 4);
            ushort4 u6 = *(const ushort4*)(Hpre + (size_t)s6 * 128 + c * 4);
            ushort4 u7 = *(const ushort4*)(Hpre + (size_t)s7 * 128 + c * 4);
            ACC1(u0, a0, p);
            ACC1(u1, a1, p);
            ACC1(u2, a2, p);
            ACC1(u3, a3, p);
            ACC1(u4, a4, p);
            ACC1(u5, a5, p);
            ACC1(u6, a6, p);
            ACC1(u7, a7, p);
        }
        for (; k < cnt; ++k) {
            int s0 = s_lds[wave][g][k];
            float a0 = w_lds[wave][g][k];
            ushort4 u0 = *(const ushort4*)(Hpre + (size_t)s0 * 128 + c * 4);
            ACC1(u0, a0, p);
        }
    }
#pragma unroll
    for (int off = 16; off >= 1; off >>= 1) z += __shfl_xor(z, off, 64);
    const float rz = 1.f / (z + 1e-16f);
    float4 bv = ((const float4*)bias)[c];
    float ox = p.x * rz + bv.x, oy = p.y * rz + bv.y;
    float oz = p.z * rz + bv.z, ow = p.w * rz + bv.w;
    ox = (ox > 0.f) ? ox : __expf(ox) - 1.f;
    oy = (oy > 0.f) ? oy : __expf(oy) - 1.f;
    oz = (oz > 0.f) ? oz : __expf(oz) - 1.f;
    ow = (ow > 0.f) ? ow : __expf(ow) - 1.f;
    ushort4 o;
    o.x = f2bf(ox); o.y = f2bf(oy); o.z = f2bf(oz); o.w = f2bf(ow);
    *(ushort4*)(out + (size_t)node * 128 + c * 4) = o;
}

// ------------------------- global mean pool (chunk-parallel) --------------

__global__ __launch_bounds__(256) void pool_partial(const unsigned short* __restrict__ h2,
                                                    const int* __restrict__ batch,
                                                    float* __restrict__ xsum,
                                                    int* __restrict__ cnt, int N) {
    const int base = blockIdx.x * PCHUNK;
    const int rg = threadIdx.x >> 6;
    const int c2 = threadIdx.x & 63;
    float ax = 0.f, ay = 0.f;
    int gcur = -1, run = 0;
    for (int r = rg; r < PCHUNK; r += 4) {
        int i = base + r;
        if (i >= N) break;
        int g = batch[i];
        if (g != gcur) {
            if (gcur >= 0) {
                atomicAdd(&xsum[gcur * 128 + c2 * 2 + 0], ax);
                atomicAdd(&xsum[gcur * 128 + c2 * 2 + 1], ay);
                if (c2 == 0) atomicAdd(&cnt[gcur], run);
            }
            gcur = g; ax = 0.f; ay = 0.f; run = 0;
        }
        ushort2 u = *(const ushort2*)(h2 + (size_t)i * 128 + c2 * 2);
        ax += bf2f(u.x); ay += bf2f(u.y);
        run += 1;
    }
    if (gcur >= 0) {
        atomicAdd(&xsum[gcur * 128 + c2 * 2 + 0], ax);
        atomicAdd(&xsum[gcur * 128 + c2 * 2 + 1], ay);
        if (c2 == 0) atomicAdd(&cnt[gcur], run);
    }
}

// ------------------------- policy / value heads ---------------------------

__global__ void head_kernel(const float* __restrict__ xsum, const int* __restrict__ cnt,
                            const float* __restrict__ Wp, const float* __restrict__ bp,
                            const float* __restrict__ Wv, const float* __restrict__ bv,
                            float* __restrict__ out) {
    int g = blockIdx.x, t = threadIdx.x;  // 64 threads
    __shared__ float p[128];
    float inv = 1.f / fmaxf((float)cnt[g], 1.f);
    p[t] = xsum[g * 128 + t] * inv;
    p[t + 64] = xsum[g * 128 + t + 64] * inv;
    __syncthreads();
    if (t < 32) {
        float acc = bp[t];
        for (int k = 0; k < 128; ++k) acc += p[k] * Wp[k * 32 + t];
        out[g * 32 + t] = acc;
    } else if (t == 32) {
        float acc = bv[0];
        for (int k = 0; k < 128; ++k) acc += p[k] * Wv[k];
        out[64 * 32 + g] = acc;
    }
}

// ---------------------------------------------------------------------------

extern "C" void kernel_launch(void* const* d_in, const int* in_sizes, int n_in,
                              void* d_out, int out_size, void* d_ws, size_t ws_size,
                              hipStream_t stream) {
    const float* x      = (const float*)d_in[0];
    const int*   ei     = (const int*)d_in[1];
    const int*   batch  = (const int*)d_in[2];
    const float* W1     = (const float*)d_in[3];
    const float* a_src1 = (const float*)d_in[4];
    const float* a_dst1 = (const float*)d_in[5];
    const float* b1     = (const float*)d_in[6];
    const float* W2     = (const float*)d_in[7];
    const float* a_src2 = (const float*)d_in[8];
    const float* a_dst2 = (const float*)d_in[9];
    const float* b2     = (const float*)d_in[10];
    const float* Wp     = (const float*)d_in[11];
    const float* bp     = (const float*)d_in[12];
    const float* Wv     = (const float*)d_in[13];
    const float* bv     = (const float*)d_in[14];

    const int N  = in_sizes[0] / 128;
    const int E  = in_sizes[1] / 2;
    const int ET = E + N;
    const int NPAD = ((N + 63) / 64) * 64;
    const int NBLK32 = NPAD / 32;
    const int PBLK = (N + PCHUNK - 1) / PCHUNK;
    const int NB = (N + 63) >> BSH;
    const int CHUNK = (ET + NBLK_H - 1) / NBLK_H;
    const int M = NB * NBLK_H;
    const int TILESH = (M + 1023) / 1024;           // <=256
    const int AB = (N + 3) / 4;
    const int GB = (N + 7) / 8;                     // agg blocks (8 nodes each)

    char* ws = (char*)d_ws;
    size_t off = 0;
    auto alloc = [&](size_t bytes) -> void* {
        void* p = ws + off;
        off = (off + bytes + 255) & ~(size_t)255;
        return p;
    };
    unsigned short* xbf   = (unsigned short*)alloc((size_t)NPAD * 128 * 2);
    unsigned short* aggx  = (unsigned short*)alloc((size_t)2 * NPAD * 128 * 2);
    unsigned short* h2pre = (unsigned short*)alloc((size_t)NPAD * 128 * 2);
    unsigned short* h2bf  = (unsigned short*)alloc((size_t)N * 128 * 2);
    unsigned short* w1h0  = (unsigned short*)alloc((size_t)128 * 128 * 2);
    unsigned short* w1h1  = (unsigned short*)alloc((size_t)128 * 128 * 2);
    unsigned short* w2sw  = (unsigned short*)alloc((size_t)256 * 128 * 2);
    float* v1s = (float*)alloc(256 * 4);
    float* v1d = (float*)alloc(256 * 4);
    float* es1 = (float*)alloc((size_t)N * 2 * 4);
    float* ed1 = (float*)alloc((size_t)N * 2 * 4);
    float* es2 = (float*)alloc((size_t)N * 4);
    float* ed2 = (float*)alloc((size_t)N * 4);
    // contiguous zero region: xsum | cnt
    const int ZINTS = 64 * 128 + 64;
    int*   zbase  = (int*)alloc(((size_t)ZINTS + 8) * 4);
    float* xsum   = (float*)zbase;
    int*   cnt    = (int*)(xsum + 64 * 128);
    int*    rowptr    = (int*)alloc((size_t)(N + 1) * 4);
    int*    hist      = (int*)alloc((size_t)M * 4);
    int*    segbase   = (int*)alloc((size_t)(NB + 1) * 4);
    int*    bsorted   = (int*)alloc((size_t)ET * 4);
    int*    csrsrc    = (int*)alloc((size_t)ET * 4);
    int*    tsum      = (int*)alloc(256 * 4);
    const int zn4 = (ZINTS + 3) / 4;
    const int ZB = (zn4 + 255) / 256;

    // 1. init: swizzles + v1 + zero + edge histogram
    init_kernel<<<33 + ZB + NBLK_H, 256, 0, stream>>>(W1, W2, a_src1, a_dst1,
                                                      w1h0, w1h1, w2sw, v1s, v1d,
                                                      zbase, zn4, ZB,
                                                      ei, hist, E, ET, CHUNK, NB);
    // 2. hist tile-scan + attn1 coefs + x cast
    scan_attn1<<<TILESH + AB, 256, 0, stream>>>(hist, tsum, M, TILESH,
                                                x, v1s, v1d, es1, ed1, xbf, N);
    // 3. partition (folds global scan; blk0 emits segbase)
    part_kernel<<<NBLK_H, 256, 0, stream>>>(ei, hist, tsum, bsorted, segbase,
                                            E, ET, CHUNK, NB, TILESH);
    // 4. per-bucket counting sort -> rowptr + csr_src
    bucket_kernel<<<NB, 256, 0, stream>>>(bsorted, segbase, csrsrc, rowptr, N, NB);
    // 5. layer-1 aggregation (2 nodes/wave, inline softmax, 8-deep)
    gat_agg_x<<<GB, 256, 0, stream>>>(xbf, es1, ed1, rowptr, csrsrc, aggx, N, NPAD);
    // 6. fused layer-1 + layer-2 GEMM, 32-row tiles (+es2/ed2 epilogue)
    gemm12_fused<<<NBLK32, 256, 0, stream>>>(aggx, w1h0, w1h1, w2sw, b1,
                                             a_src2, a_dst2, es2, ed2, h2pre, N, NPAD);
    // 7. layer-2 aggregation (2 nodes/wave, inline softmax, 8-deep)
    gat_agg_h1<<<GB, 256, 0, stream>>>(h2pre, es2, ed2, rowptr, csrsrc, b2, h2bf, N);
    // 8/9. pool + heads
    pool_partial<<<PBLK, 256, 0, stream>>>(h2bf, batch, xsum, cnt, N);
    head_kernel<<<64, 64, 0, stream>>>(xsum, cnt, Wp, bp, Wv, bv, (float*)d_out);
}